// Round 1
// baseline (1591.573 us; speedup 1.0000x reference)
//
#include <hip/hip_runtime.h>
#include <hip/hip_bf16.h>

typedef unsigned short u16;
typedef short short8 __attribute__((ext_vector_type(8)));
typedef float fvec4 __attribute__((ext_vector_type(4)));

#define NR 8192
#define ED 512

__device__ inline u16 f2bf(float f) {
    union { float f; unsigned u; } c; c.f = f;
    unsigned u = c.u;
    u += 0x7FFFu + ((u >> 16) & 1u);
    return (u16)(u >> 16);
}

__device__ inline short8 load_cvt8(const float* p) {
    const fvec4* q = (const fvec4*)p;
    fvec4 a = q[0], b = q[1];
    short8 r;
    r[0] = (short)f2bf(a[0]); r[1] = (short)f2bf(a[1]);
    r[2] = (short)f2bf(a[2]); r[3] = (short)f2bf(a[3]);
    r[4] = (short)f2bf(b[0]); r[5] = (short)f2bf(b[1]);
    r[6] = (short)f2bf(b[2]); r[7] = (short)f2bf(b[3]);
    return r;
}

// Kernel 1: q = x@Wq^T + bq (bf16), k likewise, v likewise but stored transposed.
// Each wave computes a 16x64 output tile; K=512 loop of 16x16x32 MFMAs.
__global__ __launch_bounds__(256) void qkv_kernel(
    const float* __restrict__ x,
    const float* __restrict__ Wq, const float* __restrict__ bq,
    const float* __restrict__ Wk, const float* __restrict__ bk,
    const float* __restrict__ Wv, const float* __restrict__ bv,
    u16* __restrict__ qb, u16* __restrict__ kb, u16* __restrict__ vT)
{
    const int lane = threadIdx.x & 63;
    const int wv = threadIdx.x >> 6;
    const int ln = lane & 15;
    const int kg = lane >> 4;
    const int z = blockIdx.z;

    const float* W = (z == 0) ? Wq : (z == 1) ? Wk : Wv;
    const float* bias = (z == 0) ? bq : (z == 1) ? bk : bv;

    const int m0 = blockIdx.y * 64 + wv * 16;
    const int n0 = blockIdx.x * 64;

    fvec4 acc[4];
    #pragma unroll
    for (int e = 0; e < 4; ++e) acc[e] = (fvec4){0.f, 0.f, 0.f, 0.f};

    const float* xrow = x + (size_t)(m0 + ln) * ED;
    for (int k0 = 0; k0 < ED; k0 += 32) {
        const int ko = k0 + kg * 8;
        short8 af = load_cvt8(xrow + ko);
        #pragma unroll
        for (int e = 0; e < 4; ++e) {
            short8 bf8 = load_cvt8(W + (size_t)(n0 + e * 16 + ln) * ED + ko);
            acc[e] = __builtin_amdgcn_mfma_f32_16x16x32_bf16(af, bf8, acc[e], 0, 0, 0);
        }
    }
    #pragma unroll
    for (int e = 0; e < 4; ++e) {
        const int col = n0 + e * 16 + ln;
        const float bc = bias[col];
        #pragma unroll
        for (int r = 0; r < 4; ++r) {
            const int row = m0 + kg * 4 + r;
            u16 val = f2bf(acc[e][r] + bc);
            if (z == 0)      qb[(size_t)row * ED + col] = val;
            else if (z == 1) kb[(size_t)row * ED + col] = val;
            else             vT[(size_t)col * NR + row] = val;
        }
    }
}

// Kernel 2 (fused): per block of 16 q-rows:
//   phase 1: row sum-of-squares of s = q@k^T (full row, recompute tiles)
//   phase 2: recompute s, p = exp(s/norm), PV accumulate + denominator, divide.
__global__ __launch_bounds__(256) void attn_kernel(
    const u16* __restrict__ qb, const u16* __restrict__ kb,
    const u16* __restrict__ vT, float* __restrict__ out)
{
    __shared__ u16 p_lds[16 * 64];
    __shared__ float red[4][16];

    const int lane = threadIdx.x & 63;
    const int wv = threadIdx.x >> 6;
    const int ln = lane & 15;
    const int kg = lane >> 4;
    const int m0 = blockIdx.x * 16;

    // Preload A fragments (my 16 q-rows, all K=512) into registers: 16 x short8.
    short8 afr[16];
    {
        const u16* qrow = qb + (size_t)(m0 + ln) * ED + kg * 8;
        #pragma unroll
        for (int t = 0; t < 16; ++t)
            afr[t] = *(const short8*)(qrow + t * 32);
    }

    // ---- Phase 1: sum of squares per row ----
    float ss[4] = {0.f, 0.f, 0.f, 0.f};
    for (int jt = wv; jt < NR / 16; jt += 4) {
        fvec4 acc = (fvec4){0.f, 0.f, 0.f, 0.f};
        const u16* krow = kb + (size_t)(jt * 16 + ln) * ED + kg * 8;
        #pragma unroll
        for (int t = 0; t < 16; ++t) {
            short8 bfr = *(const short8*)(krow + t * 32);
            acc = __builtin_amdgcn_mfma_f32_16x16x32_bf16(afr[t], bfr, acc, 0, 0, 0);
        }
        #pragma unroll
        for (int r = 0; r < 4; ++r) ss[r] += acc[r] * acc[r];
    }
    #pragma unroll
    for (int r = 0; r < 4; ++r) {
        float v = ss[r];
        v += __shfl_xor(v, 1); v += __shfl_xor(v, 2);
        v += __shfl_xor(v, 4); v += __shfl_xor(v, 8);
        ss[r] = v;
    }
    if (ln == 0) {
        #pragma unroll
        for (int r = 0; r < 4; ++r) red[wv][kg * 4 + r] = ss[r];
    }
    __syncthreads();
    float rn[4];
    #pragma unroll
    for (int r = 0; r < 4; ++r) {
        const int row = kg * 4 + r;
        float tot = red[0][row] + red[1][row] + red[2][row] + red[3][row];
        rn[r] = 1.0f / fmaxf(sqrtf(tot), 1e-12f);
    }
    __syncthreads();

    // ---- Phase 2: softmax + PV ----
    fvec4 oacc[8];
    #pragma unroll
    for (int e = 0; e < 8; ++e) oacc[e] = (fvec4){0.f, 0.f, 0.f, 0.f};
    float dsum[4] = {0.f, 0.f, 0.f, 0.f};

    for (int c = 0; c < NR / 64; ++c) {
        const int j0 = c * 64 + wv * 16;
        fvec4 acc = (fvec4){0.f, 0.f, 0.f, 0.f};
        const u16* krow = kb + (size_t)(j0 + ln) * ED + kg * 8;
        #pragma unroll
        for (int t = 0; t < 16; ++t) {
            short8 bfr = *(const short8*)(krow + t * 32);
            acc = __builtin_amdgcn_mfma_f32_16x16x32_bf16(afr[t], bfr, acc, 0, 0, 0);
        }
        #pragma unroll
        for (int r = 0; r < 4; ++r) {
            float p = __expf(acc[r] * rn[r]);
            dsum[r] += p;
            p_lds[(kg * 4 + r) * 64 + wv * 16 + ln] = f2bf(p);
        }
        __syncthreads();
        // PV: out[16 x 512] += p[16 x 64] @ v[64 x 512]; wave wv owns E cols [wv*128, wv*128+128)
        const u16* vbase = vT + (size_t)(wv * 128 + ln) * NR + c * 64 + kg * 8;
        #pragma unroll
        for (int kk = 0; kk < 2; ++kk) {
            short8 afp = *(const short8*)&p_lds[ln * 64 + kk * 32 + kg * 8];
            #pragma unroll
            for (int e = 0; e < 8; ++e) {
                short8 bfr = *(const short8*)(vbase + (size_t)(e * 16) * NR + kk * 32);
                oacc[e] = __builtin_amdgcn_mfma_f32_16x16x32_bf16(afp, bfr, oacc[e], 0, 0, 0);
            }
        }
        __syncthreads();
    }

    // Denominator reduce + write out
    #pragma unroll
    for (int r = 0; r < 4; ++r) {
        float v = dsum[r];
        v += __shfl_xor(v, 1); v += __shfl_xor(v, 2);
        v += __shfl_xor(v, 4); v += __shfl_xor(v, 8);
        dsum[r] = v;
    }
    __syncthreads();
    if (ln == 0) {
        #pragma unroll
        for (int r = 0; r < 4; ++r) red[wv][kg * 4 + r] = dsum[r];
    }
    __syncthreads();
    #pragma unroll
    for (int r = 0; r < 4; ++r) {
        const int row = kg * 4 + r;
        const float inv = 1.0f / (red[0][row] + red[1][row] + red[2][row] + red[3][row]);
        #pragma unroll
        for (int e = 0; e < 8; ++e)
            out[(size_t)(m0 + row) * ED + wv * 128 + e * 16 + ln] = oacc[e][r] * inv;
    }
}

extern "C" void kernel_launch(void* const* d_in, const int* in_sizes, int n_in,
                              void* d_out, int out_size, void* d_ws, size_t ws_size,
                              hipStream_t stream) {
    const float* x  = (const float*)d_in[0];
    const float* Wq = (const float*)d_in[1];
    const float* bq = (const float*)d_in[2];
    const float* Wk = (const float*)d_in[3];
    const float* bk = (const float*)d_in[4];
    const float* Wv = (const float*)d_in[5];
    const float* bv = (const float*)d_in[6];
    float* out = (float*)d_out;

    u16* qb = (u16*)d_ws;                       // 8192*512 bf16 = 8 MB
    u16* kb = qb + (size_t)NR * ED;             // 8 MB
    u16* vT = kb + (size_t)NR * ED;             // v transposed [512][8192], 8 MB

    dim3 g1(ED / 64, NR / 64, 3);
    qkv_kernel<<<g1, 256, 0, stream>>>(x, Wq, bq, Wk, bk, Wv, bv, qb, kb, vT);
    attn_kernel<<<NR / 16, 256, 0, stream>>>(qb, kb, vT, out);
}

// Round 2
// 1416.814 us; speedup vs baseline: 1.1233x; 1.1233x over previous
//
#include <hip/hip_runtime.h>
#include <hip/hip_bf16.h>

typedef unsigned short u16;
typedef short short8 __attribute__((ext_vector_type(8)));
typedef float fvec4 __attribute__((ext_vector_type(4)));

#define NR 8192
#define ED 512
#define PSTR 264  // p_lds row stride in u16; 264*2=528 B = 16B-aligned, spreads banks

__device__ inline u16 f2bf(float f) {
    union { float f; unsigned u; } c; c.f = f;
    unsigned u = c.u;
    u += 0x7FFFu + ((u >> 16) & 1u);
    return (u16)(u >> 16);
}
__device__ inline float bf2f(u16 h) {
    union { unsigned u; float f; } c; c.u = ((unsigned)h) << 16; return c.f;
}
__device__ inline short8 load_cvt8(const float* p) {
    const fvec4* q = (const fvec4*)p;
    fvec4 a = q[0], b = q[1];
    short8 r;
    r[0] = (short)f2bf(a[0]); r[1] = (short)f2bf(a[1]);
    r[2] = (short)f2bf(a[2]); r[3] = (short)f2bf(a[3]);
    r[4] = (short)f2bf(b[0]); r[5] = (short)f2bf(b[1]);
    r[6] = (short)f2bf(b[2]); r[7] = (short)f2bf(b[3]);
    return r;
}

// K0: one-shot f32 -> bf16 conversion of x and the three W's.
__global__ __launch_bounds__(256) void cvt_kernel(
    const float* __restrict__ x, const float* __restrict__ Wq,
    const float* __restrict__ Wk, const float* __restrict__ Wv,
    u16* __restrict__ xb, u16* __restrict__ wb)
{
    int tid = blockIdx.x * 256 + threadIdx.x;  // 2432*256 = 622592 chunks of 8
    const float* src; u16* dst; int off;
    if (tid < 524288)      { src = x;  dst = xb;          off = tid; }
    else if (tid < 557056) { src = Wq; dst = wb;          off = tid - 524288; }
    else if (tid < 589824) { src = Wk; dst = wb + 262144; off = tid - 557056; }
    else                   { src = Wv; dst = wb + 524288; off = tid - 589824; }
    *(short8*)(dst + (size_t)off * 8) = load_cvt8(src + (size_t)off * 8);
}

// K1: q = x@Wq^T+bq (row-major), k (row-major AND transposed), v (transposed).
__global__ __launch_bounds__(256) void qkv_kernel(
    const u16* __restrict__ xb, const u16* __restrict__ wb,
    const float* __restrict__ bq, const float* __restrict__ bk, const float* __restrict__ bv,
    u16* __restrict__ qb, u16* __restrict__ kb, u16* __restrict__ kT, u16* __restrict__ vT)
{
    const int lane = threadIdx.x & 63;
    const int wv = threadIdx.x >> 6;
    const int ln = lane & 15;
    const int kg = lane >> 4;
    const int z = blockIdx.z;

    const u16* W = wb + (size_t)z * 262144;
    const float* bias = (z == 0) ? bq : (z == 1) ? bk : bv;

    const int m0 = blockIdx.y * 64 + wv * 16;
    const int n0 = blockIdx.x * 64;

    fvec4 acc[4];
    #pragma unroll
    for (int e = 0; e < 4; ++e) acc[e] = (fvec4){0.f, 0.f, 0.f, 0.f};

    const u16* xrow = xb + (size_t)(m0 + ln) * ED + kg * 8;
    const u16* wrow = W + (size_t)(n0 + ln) * ED + kg * 8;
    #pragma unroll 4
    for (int t = 0; t < 16; ++t) {
        short8 af = *(const short8*)(xrow + t * 32);
        #pragma unroll
        for (int e = 0; e < 4; ++e) {
            short8 bf8 = *(const short8*)(wrow + (size_t)e * 16 * ED + t * 32);
            acc[e] = __builtin_amdgcn_mfma_f32_16x16x32_bf16(af, bf8, acc[e], 0, 0, 0);
        }
    }
    #pragma unroll
    for (int e = 0; e < 4; ++e) {
        const int col = n0 + e * 16 + ln;
        const float bc = bias[col];
        #pragma unroll
        for (int r = 0; r < 4; ++r) {
            const int row = m0 + kg * 4 + r;
            u16 val = f2bf(acc[e][r] + bc);
            if (z == 0) {
                qb[(size_t)row * ED + col] = val;
            } else if (z == 1) {
                kb[(size_t)row * ED + col] = val;
                kT[(size_t)col * NR + row] = val;
            } else {
                vT[(size_t)col * NR + row] = val;
            }
        }
    }
}

// K2: G = K^T K  (512x512, f32 accum, stored bf16). Each wave one 16x16 tile.
__global__ __launch_bounds__(256) void gram_kernel(
    const u16* __restrict__ kT, u16* __restrict__ Gb)
{
    const int lane = threadIdx.x & 63;
    const int ln = lane & 15;
    const int kg = lane >> 4;
    const int idx = blockIdx.x * 4 + (threadIdx.x >> 6);  // 0..1023
    const int i0 = (idx >> 5) * 16, l0 = (idx & 31) * 16;

    fvec4 acc = (fvec4){0.f, 0.f, 0.f, 0.f};
    const u16* arow = kT + (size_t)(i0 + ln) * NR + kg * 8;
    const u16* brow = kT + (size_t)(l0 + ln) * NR + kg * 8;
    #pragma unroll 8
    for (int t = 0; t < 256; ++t) {
        acc = __builtin_amdgcn_mfma_f32_16x16x32_bf16(
            *(const short8*)(arow + t * 32), *(const short8*)(brow + t * 32), acc, 0, 0, 0);
    }
    #pragma unroll
    for (int r = 0; r < 4; ++r)
        Gb[(size_t)(i0 + kg * 4 + r) * ED + l0 + ln] = f2bf(acc[r]);
}

// K3: rn[r] = 1/max(sqrt(q_r^T G q_r), eps)  via Y = Q@G then rowsum(Q.*Y).
__global__ __launch_bounds__(256) void rn_kernel(
    const u16* __restrict__ qb, const u16* __restrict__ Gb, float* __restrict__ rn)
{
    const int lane = threadIdx.x & 63;
    const int wv = threadIdx.x >> 6;
    const int ln = lane & 15;
    const int kg = lane >> 4;
    const int m0 = blockIdx.x * 64 + wv * 16;

    short8 afr[16];
    const u16* qrow = qb + (size_t)(m0 + ln) * ED + kg * 8;
    #pragma unroll
    for (int t = 0; t < 16; ++t) afr[t] = *(const short8*)(qrow + t * 32);

    float ss[4] = {0.f, 0.f, 0.f, 0.f};
    for (int e = 0; e < 32; ++e) {
        fvec4 acc = (fvec4){0.f, 0.f, 0.f, 0.f};
        const u16* grow = Gb + (size_t)(e * 16 + ln) * ED + kg * 8;
        #pragma unroll
        for (int t = 0; t < 16; ++t)
            acc = __builtin_amdgcn_mfma_f32_16x16x32_bf16(afr[t], *(const short8*)(grow + t * 32), acc, 0, 0, 0);
        #pragma unroll
        for (int r = 0; r < 4; ++r)
            ss[r] += acc[r] * bf2f(qb[(size_t)(m0 + kg * 4 + r) * ED + e * 16 + ln]);
    }
    #pragma unroll
    for (int r = 0; r < 4; ++r) {
        float v = ss[r];
        v += __shfl_xor(v, 1); v += __shfl_xor(v, 2);
        v += __shfl_xor(v, 4); v += __shfl_xor(v, 8);
        ss[r] = v;
    }
    if (ln == 0) {
        #pragma unroll
        for (int r = 0; r < 4; ++r)
            rn[m0 + kg * 4 + r] = 1.0f / fmaxf(sqrtf(ss[r]), 1e-12f);
    }
}

// K4: fused softmax(s/||s||) @ v, single pass over j. BM=32 rows/block, 8 waves.
__global__ __launch_bounds__(512, 2) void attn_kernel(
    const u16* __restrict__ qb, const u16* __restrict__ kb,
    const u16* __restrict__ vT, const float* __restrict__ rn, float* __restrict__ out)
{
    __shared__ u16 p_lds[2 * 16 * PSTR];
    __shared__ float red[2][4][16];

    const int lane = threadIdx.x & 63;
    const int w = threadIdx.x >> 6;
    const int ln = lane & 15;
    const int kg = lane >> 4;
    const int rh = w >> 2;     // row-half (0,1)
    const int jg = w & 3;      // j-quarter AND E-quarter
    const int R0 = blockIdx.x * 32 + rh * 16;

    short8 afr[16];
    const u16* qrow = qb + (size_t)(R0 + ln) * ED + kg * 8;
    #pragma unroll
    for (int t = 0; t < 16; ++t) afr[t] = *(const short8*)(qrow + t * 32);

    float rnv[4];
    #pragma unroll
    for (int r = 0; r < 4; ++r) rnv[r] = rn[R0 + kg * 4 + r];

    fvec4 oacc[8];
    #pragma unroll
    for (int e = 0; e < 8; ++e) oacc[e] = (fvec4){0.f, 0.f, 0.f, 0.f};
    float dsum[4] = {0.f, 0.f, 0.f, 0.f};

    u16* pw = p_lds + rh * 16 * PSTR;

    for (int c = 0; c < 32; ++c) {
        const int j0 = c * 256 + jg * 64;
        fvec4 acc[4];
        #pragma unroll
        for (int jt = 0; jt < 4; ++jt) acc[jt] = (fvec4){0.f, 0.f, 0.f, 0.f};
        const u16* kbase = kb + (size_t)(j0 + ln) * ED + kg * 8;
        #pragma unroll 4
        for (int t = 0; t < 16; ++t) {
            short8 af = afr[t];
            #pragma unroll
            for (int jt = 0; jt < 4; ++jt) {
                short8 bfr = *(const short8*)(kbase + (size_t)jt * 16 * ED + t * 32);
                acc[jt] = __builtin_amdgcn_mfma_f32_16x16x32_bf16(af, bfr, acc[jt], 0, 0, 0);
            }
        }
        #pragma unroll
        for (int jt = 0; jt < 4; ++jt) {
            #pragma unroll
            for (int r = 0; r < 4; ++r) {
                float p = __expf(acc[jt][r] * rnv[r]);
                dsum[r] += p;
                pw[(kg * 4 + r) * PSTR + jg * 64 + jt * 16 + ln] = f2bf(p);
            }
        }
        __syncthreads();
        const u16* vbase = vT + (size_t)(jg * 128 + ln) * NR + c * 256 + kg * 8;
        const u16* prow = pw + ln * PSTR + kg * 8;
        #pragma unroll
        for (int kk = 0; kk < 8; ++kk) {
            short8 afp = *(const short8*)(prow + kk * 32);
            #pragma unroll
            for (int e = 0; e < 8; ++e) {
                short8 bfr = *(const short8*)(vbase + (size_t)e * 16 * NR + kk * 32);
                oacc[e] = __builtin_amdgcn_mfma_f32_16x16x32_bf16(afp, bfr, oacc[e], 0, 0, 0);
            }
        }
        __syncthreads();
    }

    #pragma unroll
    for (int r = 0; r < 4; ++r) {
        float v = dsum[r];
        v += __shfl_xor(v, 1); v += __shfl_xor(v, 2);
        v += __shfl_xor(v, 4); v += __shfl_xor(v, 8);
        dsum[r] = v;
    }
    if (ln == 0) {
        #pragma unroll
        for (int r = 0; r < 4; ++r) red[rh][jg][kg * 4 + r] = dsum[r];
    }
    __syncthreads();
    float inv[4];
    #pragma unroll
    for (int r = 0; r < 4; ++r) {
        const int row = kg * 4 + r;
        inv[r] = 1.0f / (red[rh][0][row] + red[rh][1][row] + red[rh][2][row] + red[rh][3][row]);
    }
    #pragma unroll
    for (int e = 0; e < 8; ++e) {
        #pragma unroll
        for (int r = 0; r < 4; ++r)
            out[(size_t)(R0 + kg * 4 + r) * ED + jg * 128 + e * 16 + ln] = oacc[e][r] * inv[r];
    }
}

extern "C" void kernel_launch(void* const* d_in, const int* in_sizes, int n_in,
                              void* d_out, int out_size, void* d_ws, size_t ws_size,
                              hipStream_t stream) {
    const float* x  = (const float*)d_in[0];
    const float* Wq = (const float*)d_in[1];
    const float* bq = (const float*)d_in[2];
    const float* Wk = (const float*)d_in[3];
    const float* bk = (const float*)d_in[4];
    const float* Wv = (const float*)d_in[5];
    const float* bv = (const float*)d_in[6];
    float* out = (float*)d_out;

    u16* xb = (u16*)d_ws;                         // 8 MB
    u16* wb = xb + (size_t)NR * ED;               // 1.5 MB (Wq,Wk,Wv bf16)
    u16* qb = wb + 3 * 262144;                    // 8 MB
    u16* kb = qb + (size_t)NR * ED;               // 8 MB
    u16* kT = kb + (size_t)NR * ED;               // 8 MB
    u16* vT = kT + (size_t)NR * ED;               // 8 MB
    u16* Gb = vT + (size_t)NR * ED;               // 0.5 MB
    float* rn = (float*)(Gb + 262144);            // 32 KB

    cvt_kernel<<<2432, 256, 0, stream>>>(x, Wq, Wk, Wv, xb, wb);
    dim3 g1(ED / 64, NR / 64, 3);
    qkv_kernel<<<g1, 256, 0, stream>>>(xb, wb, bq, bk, bv, qb, kb, kT, vT);
    gram_kernel<<<256, 256, 0, stream>>>(kT, Gb);
    rn_kernel<<<128, 256, 0, stream>>>(qb, Gb, rn);
    attn_kernel<<<NR / 32, 512, 0, stream>>>(qb, kb, vT, rn, out);
}

// Round 3
// 544.893 us; speedup vs baseline: 2.9209x; 2.6002x over previous
//
#include <hip/hip_runtime.h>
#include <hip/hip_bf16.h>

typedef unsigned short u16;
typedef unsigned int u32;
typedef short short8 __attribute__((ext_vector_type(8)));
typedef float fvec4 __attribute__((ext_vector_type(4)));

#define NR 8192
#define ED 512
#define PSTR 264

__device__ inline u16 f2bf(float f) {
    union { float f; unsigned u; } c; c.f = f;
    unsigned u = c.u;
    u += 0x7FFFu + ((u >> 16) & 1u);
    return (u16)(u >> 16);
}
__device__ inline float bf2f(u16 h) {
    union { unsigned u; float f; } c; c.u = ((unsigned)h) << 16; return c.f;
}
__device__ inline short8 load_cvt8(const float* p) {
    const fvec4* q = (const fvec4*)p;
    fvec4 a = q[0], b = q[1];
    short8 r;
    r[0] = (short)f2bf(a[0]); r[1] = (short)f2bf(a[1]);
    r[2] = (short)f2bf(a[2]); r[3] = (short)f2bf(a[3]);
    r[4] = (short)f2bf(b[0]); r[5] = (short)f2bf(b[1]);
    r[6] = (short)f2bf(b[2]); r[7] = (short)f2bf(b[3]);
    return r;
}
__device__ inline void gload16(const void* g, void* l) {
    __builtin_amdgcn_global_load_lds(
        (const __attribute__((address_space(1))) u32*)g,
        (__attribute__((address_space(3))) u32*)l, 16, 0, 0);
}

// K0: one-shot f32 -> bf16 conversion of x and the three W's.
__global__ __launch_bounds__(256) void cvt_kernel(
    const float* __restrict__ x, const float* __restrict__ Wq,
    const float* __restrict__ Wk, const float* __restrict__ Wv,
    u16* __restrict__ xb, u16* __restrict__ wb)
{
    int tid = blockIdx.x * 256 + threadIdx.x;
    const float* src; u16* dst; int off;
    if (tid < 524288)      { src = x;  dst = xb;          off = tid; }
    else if (tid < 557056) { src = Wq; dst = wb;          off = tid - 524288; }
    else if (tid < 589824) { src = Wk; dst = wb + 262144; off = tid - 557056; }
    else                   { src = Wv; dst = wb + 524288; off = tid - 589824; }
    *(short8*)(dst + (size_t)off * 8) = load_cvt8(src + (size_t)off * 8);
}

// K1: q,k row-major; k also transposed; v transposed.
__global__ __launch_bounds__(256) void qkv_kernel(
    const u16* __restrict__ xb, const u16* __restrict__ wb,
    const float* __restrict__ bq, const float* __restrict__ bk, const float* __restrict__ bv,
    u16* __restrict__ qb, u16* __restrict__ kb, u16* __restrict__ kT, u16* __restrict__ vT)
{
    const int lane = threadIdx.x & 63;
    const int wv = threadIdx.x >> 6;
    const int ln = lane & 15;
    const int kg = lane >> 4;
    const int z = blockIdx.z;

    const u16* W = wb + (size_t)z * 262144;
    const float* bias = (z == 0) ? bq : (z == 1) ? bk : bv;

    const int m0 = blockIdx.y * 64 + wv * 16;
    const int n0 = blockIdx.x * 64;

    fvec4 acc[4];
    #pragma unroll
    for (int e = 0; e < 4; ++e) acc[e] = (fvec4){0.f, 0.f, 0.f, 0.f};

    const u16* xrow = xb + (size_t)(m0 + ln) * ED + kg * 8;
    const u16* wrow = W + (size_t)(n0 + ln) * ED + kg * 8;
    #pragma unroll 4
    for (int t = 0; t < 16; ++t) {
        short8 af = *(const short8*)(xrow + t * 32);
        #pragma unroll
        for (int e = 0; e < 4; ++e) {
            short8 bf8 = *(const short8*)(wrow + (size_t)e * 16 * ED + t * 32);
            acc[e] = __builtin_amdgcn_mfma_f32_16x16x32_bf16(af, bf8, acc[e], 0, 0, 0);
        }
    }
    #pragma unroll
    for (int e = 0; e < 4; ++e) {
        const int col = n0 + e * 16 + ln;
        const float bc = bias[col];
        #pragma unroll
        for (int r = 0; r < 4; ++r) {
            const int row = m0 + kg * 4 + r;
            u16 val = f2bf(acc[e][r] + bc);
            if (z == 0) {
                qb[(size_t)row * ED + col] = val;
            } else if (z == 1) {
                kb[(size_t)row * ED + col] = val;
                kT[(size_t)col * NR + row] = val;
            } else {
                vT[(size_t)col * NR + row] = val;
            }
        }
    }
}

// K2: G = K^T K  (512x512, f32 accum, stored bf16).
__global__ __launch_bounds__(256) void gram_kernel(
    const u16* __restrict__ kT, u16* __restrict__ Gb)
{
    const int lane = threadIdx.x & 63;
    const int ln = lane & 15;
    const int kg = lane >> 4;
    const int idx = blockIdx.x * 4 + (threadIdx.x >> 6);
    const int i0 = (idx >> 5) * 16, l0 = (idx & 31) * 16;

    fvec4 acc = (fvec4){0.f, 0.f, 0.f, 0.f};
    const u16* arow = kT + (size_t)(i0 + ln) * NR + kg * 8;
    const u16* brow = kT + (size_t)(l0 + ln) * NR + kg * 8;
    #pragma unroll 8
    for (int t = 0; t < 256; ++t) {
        acc = __builtin_amdgcn_mfma_f32_16x16x32_bf16(
            *(const short8*)(arow + t * 32), *(const short8*)(brow + t * 32), acc, 0, 0, 0);
    }
    #pragma unroll
    for (int r = 0; r < 4; ++r)
        Gb[(size_t)(i0 + kg * 4 + r) * ED + l0 + ln] = f2bf(acc[r]);
}

// K3: rn = 1/max(sqrt(q^T G q), eps)
__global__ __launch_bounds__(256) void rn_kernel(
    const u16* __restrict__ qb, const u16* __restrict__ Gb, float* __restrict__ rn)
{
    const int lane = threadIdx.x & 63;
    const int wv = threadIdx.x >> 6;
    const int ln = lane & 15;
    const int kg = lane >> 4;
    const int m0 = blockIdx.x * 64 + wv * 16;

    short8 afr[16];
    const u16* qrow = qb + (size_t)(m0 + ln) * ED + kg * 8;
    #pragma unroll
    for (int t = 0; t < 16; ++t) afr[t] = *(const short8*)(qrow + t * 32);

    float ss[4] = {0.f, 0.f, 0.f, 0.f};
    for (int e = 0; e < 32; ++e) {
        fvec4 acc = (fvec4){0.f, 0.f, 0.f, 0.f};
        const u16* grow = Gb + (size_t)(e * 16 + ln) * ED + kg * 8;
        #pragma unroll
        for (int t = 0; t < 16; ++t)
            acc = __builtin_amdgcn_mfma_f32_16x16x32_bf16(afr[t], *(const short8*)(grow + t * 32), acc, 0, 0, 0);
        #pragma unroll
        for (int r = 0; r < 4; ++r)
            ss[r] += acc[r] * bf2f(qb[(size_t)(m0 + kg * 4 + r) * ED + e * 16 + ln]);
    }
    #pragma unroll
    for (int r = 0; r < 4; ++r) {
        float v = ss[r];
        v += __shfl_xor(v, 1); v += __shfl_xor(v, 2);
        v += __shfl_xor(v, 4); v += __shfl_xor(v, 8);
        ss[r] = v;
    }
    if (ln == 0) {
        #pragma unroll
        for (int r = 0; r < 4; ++r)
            rn[m0 + kg * 4 + r] = 1.0f / fmaxf(sqrtf(ss[r]), 1e-12f);
    }
}

// K4: P = exp((Q K^T) * rn) bf16 + dsum row sums. m97-style 128x128 tile.
__global__ __launch_bounds__(256, 2) void sexp_kernel(
    const u16* __restrict__ qb, const u16* __restrict__ kb,
    const float* __restrict__ rn, u16* __restrict__ P, float* __restrict__ dsum)
{
    __shared__ u16 ldsA[128][64];
    __shared__ u16 ldsB[128][64];

    const int lane = threadIdx.x & 63;
    const int w = threadIdx.x >> 6;
    const int ln = lane & 15;
    const int kg = lane >> 4;
    const int wr = w >> 1, wc = w & 1;
    const int R0 = blockIdx.y * 128;
    const int C0 = blockIdx.x * 128;
    const int srow = lane >> 3;
    const int scol = (lane & 7) * 8;

    fvec4 acc[4][4];
    #pragma unroll
    for (int m = 0; m < 4; ++m)
        #pragma unroll
        for (int n = 0; n < 4; ++n) acc[m][n] = (fvec4){0.f, 0.f, 0.f, 0.f};

    for (int kt = 0; kt < 8; ++kt) {
        const int k0 = kt * 64;
        __syncthreads();
        #pragma unroll
        for (int i = 0; i < 4; ++i) {
            const int ra = (i * 4 + w) * 8;
            gload16(qb + (size_t)(R0 + ra + srow) * ED + k0 + scol, &ldsA[ra][0]);
            gload16(kb + (size_t)(C0 + ra + srow) * ED + k0 + scol, &ldsB[ra][0]);
        }
        __syncthreads();
        short8 af[2][4], bf8[2][4];
        #pragma unroll
        for (int kk = 0; kk < 2; ++kk) {
            #pragma unroll
            for (int m = 0; m < 4; ++m)
                af[kk][m] = *(const short8*)&ldsA[wr * 64 + m * 16 + ln][kk * 32 + kg * 8];
            #pragma unroll
            for (int n = 0; n < 4; ++n)
                bf8[kk][n] = *(const short8*)&ldsB[wc * 64 + n * 16 + ln][kk * 32 + kg * 8];
        }
        #pragma unroll
        for (int kk = 0; kk < 2; ++kk)
            #pragma unroll
            for (int m = 0; m < 4; ++m)
                #pragma unroll
                for (int n = 0; n < 4; ++n)
                    acc[m][n] = __builtin_amdgcn_mfma_f32_16x16x32_bf16(af[kk][m], bf8[kk][n], acc[m][n], 0, 0, 0);
    }

    #pragma unroll
    for (int m = 0; m < 4; ++m) {
        float dpart[4] = {0.f, 0.f, 0.f, 0.f};
        #pragma unroll
        for (int r = 0; r < 4; ++r) {
            const int grow = R0 + wr * 64 + m * 16 + kg * 4 + r;
            const float rv = rn[grow];
            #pragma unroll
            for (int n = 0; n < 4; ++n) {
                const int gcol = C0 + wc * 64 + n * 16 + ln;
                u16 pb = f2bf(__expf(acc[m][n][r] * rv));
                P[(size_t)grow * NR + gcol] = pb;
                dpart[r] += bf2f(pb);
            }
        }
        #pragma unroll
        for (int r = 0; r < 4; ++r) {
            float v = dpart[r];
            v += __shfl_xor(v, 1); v += __shfl_xor(v, 2);
            v += __shfl_xor(v, 4); v += __shfl_xor(v, 8);
            if (ln == 0)
                atomicAdd(&dsum[R0 + wr * 64 + m * 16 + kg * 4 + r], v);
        }
    }
}

// K5: out = (P @ V) / dsum.  A = P row-major, B = vT (B^T form), K = 8192.
__global__ __launch_bounds__(256, 2) void pv_kernel(
    const u16* __restrict__ P, const u16* __restrict__ vT,
    const float* __restrict__ dsum, float* __restrict__ out)
{
    __shared__ u16 ldsA[128][64];
    __shared__ u16 ldsB[128][64];

    const int lane = threadIdx.x & 63;
    const int w = threadIdx.x >> 6;
    const int ln = lane & 15;
    const int kg = lane >> 4;
    const int wr = w >> 1, wc = w & 1;
    const int R0 = blockIdx.y * 128;
    const int C0 = blockIdx.x * 128;
    const int srow = lane >> 3;
    const int scol = (lane & 7) * 8;

    fvec4 acc[4][4];
    #pragma unroll
    for (int m = 0; m < 4; ++m)
        #pragma unroll
        for (int n = 0; n < 4; ++n) acc[m][n] = (fvec4){0.f, 0.f, 0.f, 0.f};

    for (int kt = 0; kt < 128; ++kt) {
        const int k0 = kt * 64;
        __syncthreads();
        #pragma unroll
        for (int i = 0; i < 4; ++i) {
            const int ra = (i * 4 + w) * 8;
            gload16(P  + (size_t)(R0 + ra + srow) * NR + k0 + scol, &ldsA[ra][0]);
            gload16(vT + (size_t)(C0 + ra + srow) * NR + k0 + scol, &ldsB[ra][0]);
        }
        __syncthreads();
        short8 af[2][4], bf8[2][4];
        #pragma unroll
        for (int kk = 0; kk < 2; ++kk) {
            #pragma unroll
            for (int m = 0; m < 4; ++m)
                af[kk][m] = *(const short8*)&ldsA[wr * 64 + m * 16 + ln][kk * 32 + kg * 8];
            #pragma unroll
            for (int n = 0; n < 4; ++n)
                bf8[kk][n] = *(const short8*)&ldsB[wc * 64 + n * 16 + ln][kk * 32 + kg * 8];
        }
        #pragma unroll
        for (int kk = 0; kk < 2; ++kk)
            #pragma unroll
            for (int m = 0; m < 4; ++m)
                #pragma unroll
                for (int n = 0; n < 4; ++n)
                    acc[m][n] = __builtin_amdgcn_mfma_f32_16x16x32_bf16(af[kk][m], bf8[kk][n], acc[m][n], 0, 0, 0);
    }

    #pragma unroll
    for (int m = 0; m < 4; ++m) {
        #pragma unroll
        for (int r = 0; r < 4; ++r) {
            const int grow = R0 + wr * 64 + m * 16 + kg * 4 + r;
            const float iv = 1.0f / dsum[grow];
            #pragma unroll
            for (int n = 0; n < 4; ++n) {
                const int gcol = C0 + wc * 64 + n * 16 + ln;
                out[(size_t)grow * ED + gcol] = acc[m][n][r] * iv;
            }
        }
    }
}

// Fallback fused attention (R2 path) if ws is too small for P.
__global__ __launch_bounds__(512, 2) void attn_kernel(
    const u16* __restrict__ qb, const u16* __restrict__ kb,
    const u16* __restrict__ vT, const float* __restrict__ rn, float* __restrict__ out)
{
    __shared__ u16 p_lds[2 * 16 * PSTR];
    __shared__ float red[2][4][16];

    const int lane = threadIdx.x & 63;
    const int w = threadIdx.x >> 6;
    const int ln = lane & 15;
    const int kg = lane >> 4;
    const int rh = w >> 2;
    const int jg = w & 3;
    const int R0 = blockIdx.x * 32 + rh * 16;

    short8 afr[16];
    const u16* qrow = qb + (size_t)(R0 + ln) * ED + kg * 8;
    #pragma unroll
    for (int t = 0; t < 16; ++t) afr[t] = *(const short8*)(qrow + t * 32);

    float rnv[4];
    #pragma unroll
    for (int r = 0; r < 4; ++r) rnv[r] = rn[R0 + kg * 4 + r];

    fvec4 oacc[8];
    #pragma unroll
    for (int e = 0; e < 8; ++e) oacc[e] = (fvec4){0.f, 0.f, 0.f, 0.f};
    float dsum[4] = {0.f, 0.f, 0.f, 0.f};

    u16* pw = p_lds + rh * 16 * PSTR;

    for (int c = 0; c < 32; ++c) {
        const int j0 = c * 256 + jg * 64;
        fvec4 acc[4];
        #pragma unroll
        for (int jt = 0; jt < 4; ++jt) acc[jt] = (fvec4){0.f, 0.f, 0.f, 0.f};
        const u16* kbase = kb + (size_t)(j0 + ln) * ED + kg * 8;
        #pragma unroll 4
        for (int t = 0; t < 16; ++t) {
            short8 af = afr[t];
            #pragma unroll
            for (int jt = 0; jt < 4; ++jt) {
                short8 bfr = *(const short8*)(kbase + (size_t)jt * 16 * ED + t * 32);
                acc[jt] = __builtin_amdgcn_mfma_f32_16x16x32_bf16(af, bfr, acc[jt], 0, 0, 0);
            }
        }
        #pragma unroll
        for (int jt = 0; jt < 4; ++jt) {
            #pragma unroll
            for (int r = 0; r < 4; ++r) {
                float p = __expf(acc[jt][r] * rnv[r]);
                dsum[r] += p;
                pw[(kg * 4 + r) * PSTR + jg * 64 + jt * 16 + ln] = f2bf(p);
            }
        }
        __syncthreads();
        const u16* vbase = vT + (size_t)(jg * 128 + ln) * NR + c * 256 + kg * 8;
        const u16* prow = pw + ln * PSTR + kg * 8;
        #pragma unroll
        for (int kk = 0; kk < 8; ++kk) {
            short8 afp = *(const short8*)(prow + kk * 32);
            #pragma unroll
            for (int e = 0; e < 8; ++e) {
                short8 bfr = *(const short8*)(vbase + (size_t)e * 16 * NR + kk * 32);
                oacc[e] = __builtin_amdgcn_mfma_f32_16x16x32_bf16(afp, bfr, oacc[e], 0, 0, 0);
            }
        }
        __syncthreads();
    }

    #pragma unroll
    for (int r = 0; r < 4; ++r) {
        float v = dsum[r];
        v += __shfl_xor(v, 1); v += __shfl_xor(v, 2);
        v += __shfl_xor(v, 4); v += __shfl_xor(v, 8);
        dsum[r] = v;
    }
    if (ln == 0) {
        #pragma unroll
        for (int r = 0; r < 4; ++r) red[rh][jg][kg * 4 + r] = dsum[r];
    }
    __syncthreads();
    float inv[4];
    #pragma unroll
    for (int r = 0; r < 4; ++r) {
        const int row = kg * 4 + r;
        inv[r] = 1.0f / (red[rh][0][row] + red[rh][1][row] + red[rh][2][row] + red[rh][3][row]);
    }
    #pragma unroll
    for (int e = 0; e < 8; ++e) {
        #pragma unroll
        for (int r = 0; r < 4; ++r)
            out[(size_t)(R0 + kg * 4 + r) * ED + jg * 128 + e * 16 + ln] = oacc[e][r] * inv[r];
    }
}

extern "C" void kernel_launch(void* const* d_in, const int* in_sizes, int n_in,
                              void* d_out, int out_size, void* d_ws, size_t ws_size,
                              hipStream_t stream) {
    const float* x  = (const float*)d_in[0];
    const float* Wq = (const float*)d_in[1];
    const float* bq = (const float*)d_in[2];
    const float* Wk = (const float*)d_in[3];
    const float* bk = (const float*)d_in[4];
    const float* Wv = (const float*)d_in[5];
    const float* bv = (const float*)d_in[6];
    float* out = (float*)d_out;

    u16* xb = (u16*)d_ws;                          // 8 MB
    u16* wb = xb + (size_t)NR * ED;                // 1.5 MB
    u16* qb = wb + 3 * 262144;                     // 8 MB
    u16* kb = qb + (size_t)NR * ED;                // 8 MB
    u16* kT = kb + (size_t)NR * ED;                // 8 MB
    u16* vT = kT + (size_t)NR * ED;                // 8 MB
    u16* Gb = vT + (size_t)NR * ED;                // 0.5 MB
    float* rn   = (float*)(Gb + 262144);           // 32 KB
    float* dsum = rn + NR;                         // 32 KB
    u16* P = (u16*)(dsum + NR);                    // 128 MB

    const size_t need = (size_t)((u16*)(dsum + NR) - (u16*)d_ws) * 2 + (size_t)NR * NR * 2;

    cvt_kernel<<<2432, 256, 0, stream>>>(x, Wq, Wk, Wv, xb, wb);
    dim3 g1(ED / 64, NR / 64, 3);
    qkv_kernel<<<g1, 256, 0, stream>>>(xb, wb, bq, bk, bv, qb, kb, kT, vT);
    gram_kernel<<<256, 256, 0, stream>>>(kT, Gb);
    rn_kernel<<<128, 256, 0, stream>>>(qb, Gb, rn);

    if (ws_size >= need) {
        hipMemsetAsync(dsum, 0, NR * sizeof(float), stream);
        dim3 gs(NR / 128, NR / 128);
        sexp_kernel<<<gs, 256, 0, stream>>>(qb, kb, rn, P, dsum);
        dim3 gp(ED / 128, NR / 128);
        pv_kernel<<<gp, 256, 0, stream>>>(P, vT, dsum, out);
    } else {
        attn_kernel<<<NR / 32, 512, 0, stream>>>(qb, kb, vT, rn, out);
    }
}

// Round 4
// 422.264 us; speedup vs baseline: 3.7691x; 1.2904x over previous
//
#include <hip/hip_runtime.h>
#include <hip/hip_bf16.h>

typedef unsigned short u16;
typedef unsigned int u32;
typedef short short8 __attribute__((ext_vector_type(8)));
typedef float fvec4 __attribute__((ext_vector_type(4)));

#define NR 8192
#define ED 512
#define PSTR 264

__device__ inline u16 f2bf(float f) {
    union { float f; unsigned u; } c; c.f = f;
    unsigned u = c.u;
    u += 0x7FFFu + ((u >> 16) & 1u);
    return (u16)(u >> 16);
}
__device__ inline float bf2f(u16 h) {
    union { unsigned u; float f; } c; c.u = ((unsigned)h) << 16; return c.f;
}
__device__ inline short8 load_cvt8(const float* p) {
    const fvec4* q = (const fvec4*)p;
    fvec4 a = q[0], b = q[1];
    short8 r;
    r[0] = (short)f2bf(a[0]); r[1] = (short)f2bf(a[1]);
    r[2] = (short)f2bf(a[2]); r[3] = (short)f2bf(a[3]);
    r[4] = (short)f2bf(b[0]); r[5] = (short)f2bf(b[1]);
    r[6] = (short)f2bf(b[2]); r[7] = (short)f2bf(b[3]);
    return r;
}
__device__ inline void gload16(const void* g, void* l) {
    __builtin_amdgcn_global_load_lds(
        (const __attribute__((address_space(1))) u32*)g,
        (__attribute__((address_space(3))) u32*)l, 16, 0, 0);
}

// K0: one-shot f32 -> bf16 conversion of x and the three W's.
__global__ __launch_bounds__(256) void cvt_kernel(
    const float* __restrict__ x, const float* __restrict__ Wq,
    const float* __restrict__ Wk, const float* __restrict__ Wv,
    u16* __restrict__ xb, u16* __restrict__ wb)
{
    int tid = blockIdx.x * 256 + threadIdx.x;
    const float* src; u16* dst; int off;
    if (tid < 524288)      { src = x;  dst = xb;          off = tid; }
    else if (tid < 557056) { src = Wq; dst = wb;          off = tid - 524288; }
    else if (tid < 589824) { src = Wk; dst = wb + 262144; off = tid - 557056; }
    else                   { src = Wv; dst = wb + 524288; off = tid - 589824; }
    *(short8*)(dst + (size_t)off * 8) = load_cvt8(src + (size_t)off * 8);
}

// K1: 128x128-tile LDS-staged GEMM: q,k row-major; k also transposed; v transposed.
__global__ __launch_bounds__(256, 2) void qkv_kernel(
    const u16* __restrict__ xb, const u16* __restrict__ wb,
    const float* __restrict__ bq, const float* __restrict__ bk, const float* __restrict__ bv,
    u16* __restrict__ qb, u16* __restrict__ kb, u16* __restrict__ kT, u16* __restrict__ vT)
{
    __shared__ u16 ldsA[128][64];
    __shared__ u16 ldsB[128][64];

    const int lane = threadIdx.x & 63;
    const int w = threadIdx.x >> 6;
    const int ln = lane & 15;
    const int kg = lane >> 4;
    const int wr = w >> 1, wc = w & 1;
    const int z = blockIdx.z;
    const int R0 = blockIdx.y * 128;
    const int C0 = blockIdx.x * 128;
    const int srow = lane >> 3;
    const int scol = (lane & 7) * 8;

    const u16* B = wb + (size_t)z * 262144;
    const float* bias = (z == 0) ? bq : (z == 1) ? bk : bv;

    fvec4 acc[4][4];
    #pragma unroll
    for (int m = 0; m < 4; ++m)
        #pragma unroll
        for (int n = 0; n < 4; ++n) acc[m][n] = (fvec4){0.f, 0.f, 0.f, 0.f};

    for (int kt = 0; kt < 8; ++kt) {
        const int k0 = kt * 64;
        __syncthreads();
        #pragma unroll
        for (int i = 0; i < 4; ++i) {
            const int ra = (i * 4 + w) * 8;
            gload16(xb + (size_t)(R0 + ra + srow) * ED + k0 + scol, &ldsA[ra][0]);
            gload16(B  + (size_t)(C0 + ra + srow) * ED + k0 + scol, &ldsB[ra][0]);
        }
        __syncthreads();
        short8 af[2][4], bf8[2][4];
        #pragma unroll
        for (int kk = 0; kk < 2; ++kk) {
            #pragma unroll
            for (int m = 0; m < 4; ++m)
                af[kk][m] = *(const short8*)&ldsA[wr * 64 + m * 16 + ln][kk * 32 + kg * 8];
            #pragma unroll
            for (int n = 0; n < 4; ++n)
                bf8[kk][n] = *(const short8*)&ldsB[wc * 64 + n * 16 + ln][kk * 32 + kg * 8];
        }
        #pragma unroll
        for (int kk = 0; kk < 2; ++kk)
            #pragma unroll
            for (int m = 0; m < 4; ++m)
                #pragma unroll
                for (int n = 0; n < 4; ++n)
                    acc[m][n] = __builtin_amdgcn_mfma_f32_16x16x32_bf16(af[kk][m], bf8[kk][n], acc[m][n], 0, 0, 0);
    }

    #pragma unroll
    for (int n = 0; n < 4; ++n) {
        const int gcol = C0 + wc * 64 + n * 16 + ln;
        const float bc = bias[gcol];
        #pragma unroll
        for (int m = 0; m < 4; ++m) {
            #pragma unroll
            for (int r = 0; r < 4; ++r) {
                const int grow = R0 + wr * 64 + m * 16 + kg * 4 + r;
                u16 val = f2bf(acc[m][n][r] + bc);
                if (z == 0) {
                    qb[(size_t)grow * ED + gcol] = val;
                } else if (z == 1) {
                    kb[(size_t)grow * ED + gcol] = val;
                    kT[(size_t)gcol * NR + grow] = val;
                } else {
                    vT[(size_t)gcol * NR + grow] = val;
                }
            }
        }
    }
}

// K2: G = K^T K (512x512, f32 accum, stored bf16). 4 interleaved acc chains for ILP.
__global__ __launch_bounds__(256) void gram_kernel(
    const u16* __restrict__ kT, u16* __restrict__ Gb)
{
    const int lane = threadIdx.x & 63;
    const int ln = lane & 15;
    const int kg = lane >> 4;
    const int idx = blockIdx.x * 4 + (threadIdx.x >> 6);
    const int i0 = (idx >> 5) * 16, l0 = (idx & 31) * 16;

    fvec4 acc[4];
    #pragma unroll
    for (int c = 0; c < 4; ++c) acc[c] = (fvec4){0.f, 0.f, 0.f, 0.f};
    const u16* arow = kT + (size_t)(i0 + ln) * NR + kg * 8;
    const u16* brow = kT + (size_t)(l0 + ln) * NR + kg * 8;
    #pragma unroll 8
    for (int t = 0; t < 256; ++t) {
        acc[t & 3] = __builtin_amdgcn_mfma_f32_16x16x32_bf16(
            *(const short8*)(arow + t * 32), *(const short8*)(brow + t * 32), acc[t & 3], 0, 0, 0);
    }
    fvec4 s = acc[0] + acc[1] + acc[2] + acc[3];
    #pragma unroll
    for (int r = 0; r < 4; ++r)
        Gb[(size_t)(i0 + kg * 4 + r) * ED + l0 + ln] = f2bf(s[r]);
}

// K3: rn = 1/max(sqrt(q^T G q), eps), 2 acc chains.
__global__ __launch_bounds__(256) void rn_kernel(
    const u16* __restrict__ qb, const u16* __restrict__ Gb, float* __restrict__ rn)
{
    const int lane = threadIdx.x & 63;
    const int wv = threadIdx.x >> 6;
    const int ln = lane & 15;
    const int kg = lane >> 4;
    const int m0 = blockIdx.x * 64 + wv * 16;

    short8 afr[16];
    const u16* qrow = qb + (size_t)(m0 + ln) * ED + kg * 8;
    #pragma unroll
    for (int t = 0; t < 16; ++t) afr[t] = *(const short8*)(qrow + t * 32);

    float ss[4] = {0.f, 0.f, 0.f, 0.f};
    for (int e = 0; e < 32; ++e) {
        fvec4 a0 = (fvec4){0.f, 0.f, 0.f, 0.f};
        fvec4 a1 = (fvec4){0.f, 0.f, 0.f, 0.f};
        const u16* grow = Gb + (size_t)(e * 16 + ln) * ED + kg * 8;
        #pragma unroll
        for (int t = 0; t < 16; t += 2) {
            a0 = __builtin_amdgcn_mfma_f32_16x16x32_bf16(afr[t],     *(const short8*)(grow + t * 32),       a0, 0, 0, 0);
            a1 = __builtin_amdgcn_mfma_f32_16x16x32_bf16(afr[t + 1], *(const short8*)(grow + (t + 1) * 32), a1, 0, 0, 0);
        }
        fvec4 acc = a0 + a1;
        #pragma unroll
        for (int r = 0; r < 4; ++r)
            ss[r] += acc[r] * bf2f(qb[(size_t)(m0 + kg * 4 + r) * ED + e * 16 + ln]);
    }
    #pragma unroll
    for (int r = 0; r < 4; ++r) {
        float v = ss[r];
        v += __shfl_xor(v, 1); v += __shfl_xor(v, 2);
        v += __shfl_xor(v, 4); v += __shfl_xor(v, 8);
        ss[r] = v;
    }
    if (ln == 0) {
        #pragma unroll
        for (int r = 0; r < 4; ++r)
            rn[m0 + kg * 4 + r] = 1.0f / fmaxf(sqrtf(ss[r]), 1e-12f);
    }
}

// K4: P = exp((Q K^T) * rn) bf16 + dsum row sums. 128x128 tile.
__global__ __launch_bounds__(256, 2) void sexp_kernel(
    const u16* __restrict__ qb, const u16* __restrict__ kb,
    const float* __restrict__ rn, u16* __restrict__ P, float* __restrict__ dsum)
{
    __shared__ u16 ldsA[128][64];
    __shared__ u16 ldsB[128][64];

    const int lane = threadIdx.x & 63;
    const int w = threadIdx.x >> 6;
    const int ln = lane & 15;
    const int kg = lane >> 4;
    const int wr = w >> 1, wc = w & 1;
    const int R0 = blockIdx.y * 128;
    const int C0 = blockIdx.x * 128;
    const int srow = lane >> 3;
    const int scol = (lane & 7) * 8;

    fvec4 acc[4][4];
    #pragma unroll
    for (int m = 0; m < 4; ++m)
        #pragma unroll
        for (int n = 0; n < 4; ++n) acc[m][n] = (fvec4){0.f, 0.f, 0.f, 0.f};

    for (int kt = 0; kt < 8; ++kt) {
        const int k0 = kt * 64;
        __syncthreads();
        #pragma unroll
        for (int i = 0; i < 4; ++i) {
            const int ra = (i * 4 + w) * 8;
            gload16(qb + (size_t)(R0 + ra + srow) * ED + k0 + scol, &ldsA[ra][0]);
            gload16(kb + (size_t)(C0 + ra + srow) * ED + k0 + scol, &ldsB[ra][0]);
        }
        __syncthreads();
        short8 af[2][4], bf8[2][4];
        #pragma unroll
        for (int kk = 0; kk < 2; ++kk) {
            #pragma unroll
            for (int m = 0; m < 4; ++m)
                af[kk][m] = *(const short8*)&ldsA[wr * 64 + m * 16 + ln][kk * 32 + kg * 8];
            #pragma unroll
            for (int n = 0; n < 4; ++n)
                bf8[kk][n] = *(const short8*)&ldsB[wc * 64 + n * 16 + ln][kk * 32 + kg * 8];
        }
        #pragma unroll
        for (int kk = 0; kk < 2; ++kk)
            #pragma unroll
            for (int m = 0; m < 4; ++m)
                #pragma unroll
                for (int n = 0; n < 4; ++n)
                    acc[m][n] = __builtin_amdgcn_mfma_f32_16x16x32_bf16(af[kk][m], bf8[kk][n], acc[m][n], 0, 0, 0);
    }

    #pragma unroll
    for (int m = 0; m < 4; ++m) {
        float dpart[4] = {0.f, 0.f, 0.f, 0.f};
        #pragma unroll
        for (int r = 0; r < 4; ++r) {
            const int grow = R0 + wr * 64 + m * 16 + kg * 4 + r;
            const float rv = rn[grow];
            #pragma unroll
            for (int n = 0; n < 4; ++n) {
                const int gcol = C0 + wc * 64 + n * 16 + ln;
                u16 pb = f2bf(__expf(acc[m][n][r] * rv));
                P[(size_t)grow * NR + gcol] = pb;
                dpart[r] += bf2f(pb);
            }
        }
        #pragma unroll
        for (int r = 0; r < 4; ++r) {
            float v = dpart[r];
            v += __shfl_xor(v, 1); v += __shfl_xor(v, 2);
            v += __shfl_xor(v, 4); v += __shfl_xor(v, 8);
            if (ln == 0)
                atomicAdd(&dsum[R0 + wr * 64 + m * 16 + kg * 4 + r], v);
        }
    }
}

// K5: partial PV, split-K=2. part[ks][row][col] f32.
__global__ __launch_bounds__(256, 2) void pv_kernel(
    const u16* __restrict__ P, const u16* __restrict__ vT, float* __restrict__ part)
{
    __shared__ u16 ldsA[128][64];
    __shared__ u16 ldsB[128][64];

    const int lane = threadIdx.x & 63;
    const int w = threadIdx.x >> 6;
    const int ln = lane & 15;
    const int kg = lane >> 4;
    const int wr = w >> 1, wc = w & 1;
    const int R0 = blockIdx.y * 128;
    const int C0 = blockIdx.x * 128;
    const int ks = blockIdx.z;
    const int srow = lane >> 3;
    const int scol = (lane & 7) * 8;

    float* pp = part + (size_t)ks * NR * ED;

    fvec4 acc[4][4];
    #pragma unroll
    for (int m = 0; m < 4; ++m)
        #pragma unroll
        for (int n = 0; n < 4; ++n) acc[m][n] = (fvec4){0.f, 0.f, 0.f, 0.f};

    for (int kt = 0; kt < 64; ++kt) {
        const int k0 = ks * 4096 + kt * 64;
        __syncthreads();
        #pragma unroll
        for (int i = 0; i < 4; ++i) {
            const int ra = (i * 4 + w) * 8;
            gload16(P  + (size_t)(R0 + ra + srow) * NR + k0 + scol, &ldsA[ra][0]);
            gload16(vT + (size_t)(C0 + ra + srow) * NR + k0 + scol, &ldsB[ra][0]);
        }
        __syncthreads();
        short8 af[2][4], bf8[2][4];
        #pragma unroll
        for (int kk = 0; kk < 2; ++kk) {
            #pragma unroll
            for (int m = 0; m < 4; ++m)
                af[kk][m] = *(const short8*)&ldsA[wr * 64 + m * 16 + ln][kk * 32 + kg * 8];
            #pragma unroll
            for (int n = 0; n < 4; ++n)
                bf8[kk][n] = *(const short8*)&ldsB[wc * 64 + n * 16 + ln][kk * 32 + kg * 8];
        }
        #pragma unroll
        for (int kk = 0; kk < 2; ++kk)
            #pragma unroll
            for (int m = 0; m < 4; ++m)
                #pragma unroll
                for (int n = 0; n < 4; ++n)
                    acc[m][n] = __builtin_amdgcn_mfma_f32_16x16x32_bf16(af[kk][m], bf8[kk][n], acc[m][n], 0, 0, 0);
    }

    #pragma unroll
    for (int m = 0; m < 4; ++m) {
        #pragma unroll
        for (int r = 0; r < 4; ++r) {
            const int grow = R0 + wr * 64 + m * 16 + kg * 4 + r;
            #pragma unroll
            for (int n = 0; n < 4; ++n) {
                const int gcol = C0 + wc * 64 + n * 16 + ln;
                pp[(size_t)grow * ED + gcol] = acc[m][n][r];
            }
        }
    }
}

// K6: out = (part0 + part1) / dsum
__global__ __launch_bounds__(256) void reduce_kernel(
    const float* __restrict__ part, const float* __restrict__ dsum, float* __restrict__ out)
{
    const size_t idx = ((size_t)blockIdx.x * 256 + threadIdx.x) * 4;
    const int row = (int)(idx >> 9);
    const float iv = 1.0f / dsum[row];
    fvec4 a = *(const fvec4*)(part + idx);
    fvec4 b = *(const fvec4*)(part + (size_t)NR * ED + idx);
    fvec4 o;
    #pragma unroll
    for (int i = 0; i < 4; ++i) o[i] = (a[i] + b[i]) * iv;
    *(fvec4*)(out + idx) = o;
}

// Fallback fused attention (R2 path) if ws is too small for P.
__global__ __launch_bounds__(512, 2) void attn_kernel(
    const u16* __restrict__ qb, const u16* __restrict__ kb,
    const u16* __restrict__ vT, const float* __restrict__ rn, float* __restrict__ out)
{
    __shared__ u16 p_lds[2 * 16 * PSTR];
    __shared__ float red[2][4][16];

    const int lane = threadIdx.x & 63;
    const int w = threadIdx.x >> 6;
    const int ln = lane & 15;
    const int kg = lane >> 4;
    const int rh = w >> 2;
    const int jg = w & 3;
    const int R0 = blockIdx.x * 32 + rh * 16;

    short8 afr[16];
    const u16* qrow = qb + (size_t)(R0 + ln) * ED + kg * 8;
    #pragma unroll
    for (int t = 0; t < 16; ++t) afr[t] = *(const short8*)(qrow + t * 32);

    float rnv[4];
    #pragma unroll
    for (int r = 0; r < 4; ++r) rnv[r] = rn[R0 + kg * 4 + r];

    fvec4 oacc[8];
    #pragma unroll
    for (int e = 0; e < 8; ++e) oacc[e] = (fvec4){0.f, 0.f, 0.f, 0.f};
    float dsum[4] = {0.f, 0.f, 0.f, 0.f};

    u16* pw = p_lds + rh * 16 * PSTR;

    for (int c = 0; c < 32; ++c) {
        const int j0 = c * 256 + jg * 64;
        fvec4 acc[4];
        #pragma unroll
        for (int jt = 0; jt < 4; ++jt) acc[jt] = (fvec4){0.f, 0.f, 0.f, 0.f};
        const u16* kbase = kb + (size_t)(j0 + ln) * ED + kg * 8;
        #pragma unroll 4
        for (int t = 0; t < 16; ++t) {
            short8 af = afr[t];
            #pragma unroll
            for (int jt = 0; jt < 4; ++jt) {
                short8 bfr = *(const short8*)(kbase + (size_t)jt * 16 * ED + t * 32);
                acc[jt] = __builtin_amdgcn_mfma_f32_16x16x32_bf16(af, bfr, acc[jt], 0, 0, 0);
            }
        }
        #pragma unroll
        for (int jt = 0; jt < 4; ++jt) {
            #pragma unroll
            for (int r = 0; r < 4; ++r) {
                float p = __expf(acc[jt][r] * rnv[r]);
                dsum[r] += p;
                pw[(kg * 4 + r) * PSTR + jg * 64 + jt * 16 + ln] = f2bf(p);
            }
        }
        __syncthreads();
        const u16* vbase = vT + (size_t)(jg * 128 + ln) * NR + c * 256 + kg * 8;
        const u16* prow = pw + ln * PSTR + kg * 8;
        #pragma unroll
        for (int kk = 0; kk < 8; ++kk) {
            short8 afp = *(const short8*)(prow + kk * 32);
            #pragma unroll
            for (int e = 0; e < 8; ++e) {
                short8 bfr = *(const short8*)(vbase + (size_t)e * 16 * NR + kk * 32);
                oacc[e] = __builtin_amdgcn_mfma_f32_16x16x32_bf16(afp, bfr, oacc[e], 0, 0, 0);
            }
        }
        __syncthreads();
    }

    #pragma unroll
    for (int r = 0; r < 4; ++r) {
        float v = dsum[r];
        v += __shfl_xor(v, 1); v += __shfl_xor(v, 2);
        v += __shfl_xor(v, 4); v += __shfl_xor(v, 8);
        dsum[r] = v;
    }
    if (ln == 0) {
        #pragma unroll
        for (int r = 0; r < 4; ++r) red[rh][jg][kg * 4 + r] = dsum[r];
    }
    __syncthreads();
    float inv[4];
    #pragma unroll
    for (int r = 0; r < 4; ++r) {
        const int row = kg * 4 + r;
        inv[r] = 1.0f / (red[rh][0][row] + red[rh][1][row] + red[rh][2][row] + red[rh][3][row]);
    }
    #pragma unroll
    for (int e = 0; e < 8; ++e) {
        #pragma unroll
        for (int r = 0; r < 4; ++r)
            out[(size_t)(R0 + kg * 4 + r) * ED + jg * 128 + e * 16 + ln] = oacc[e][r] * inv[r];
    }
}

extern "C" void kernel_launch(void* const* d_in, const int* in_sizes, int n_in,
                              void* d_out, int out_size, void* d_ws, size_t ws_size,
                              hipStream_t stream) {
    const float* x  = (const float*)d_in[0];
    const float* Wq = (const float*)d_in[1];
    const float* bq = (const float*)d_in[2];
    const float* Wk = (const float*)d_in[3];
    const float* bk = (const float*)d_in[4];
    const float* Wv = (const float*)d_in[5];
    const float* bv = (const float*)d_in[6];
    float* out = (float*)d_out;

    u16* xb = (u16*)d_ws;                          // 8 MB
    u16* wb = xb + (size_t)NR * ED;                // 1.5 MB
    u16* qb = wb + 3 * 262144;                     // 8 MB
    u16* kb = qb + (size_t)NR * ED;                // 8 MB
    u16* kT = kb + (size_t)NR * ED;                // 8 MB
    u16* vT = kT + (size_t)NR * ED;                // 8 MB  (byte offset 33.5 MB)
    u16* Gb = vT + (size_t)NR * ED;                // 0.5 MB
    float* rn   = (float*)(Gb + 262144);           // 32 KB
    float* dsum = rn + NR;                         // 32 KB
    u16* P = (u16*)(dsum + NR);                    // 128 MB
    // pv partials (2 x 16 MB f32) alias the dead xb/wb/qb/kb/kT region (first 32 MB).
    float* part = (float*)d_ws;

    const size_t need = (size_t)((u16*)(dsum + NR) - (u16*)d_ws) * 2 + (size_t)NR * NR * 2;

    cvt_kernel<<<2432, 256, 0, stream>>>(x, Wq, Wk, Wv, xb, wb);
    dim3 g1(ED / 128, NR / 128, 3);
    qkv_kernel<<<g1, 256, 0, stream>>>(xb, wb, bq, bk, bv, qb, kb, kT, vT);
    gram_kernel<<<256, 256, 0, stream>>>(kT, Gb);
    rn_kernel<<<128, 256, 0, stream>>>(qb, Gb, rn);

    if (ws_size >= need) {
        hipMemsetAsync(dsum, 0, NR * sizeof(float), stream);
        dim3 gs(NR / 128, NR / 128);
        sexp_kernel<<<gs, 256, 0, stream>>>(qb, kb, rn, P, dsum);
        dim3 gp(ED / 128, NR / 128, 2);
        pv_kernel<<<gp, 256, 0, stream>>>(P, vT, part);
        reduce_kernel<<<NR * ED / 4 / 256, 256, 0, stream>>>(part, dsum, out);
    } else {
        attn_kernel<<<NR / 32, 512, 0, stream>>>(qb, kb, vT, rn, out);
    }
}

// Round 5
// 402.180 us; speedup vs baseline: 3.9574x; 1.0499x over previous
//
#include <hip/hip_runtime.h>
#include <hip/hip_bf16.h>

typedef unsigned short u16;
typedef unsigned int u32;
typedef short short8 __attribute__((ext_vector_type(8)));
typedef float fvec4 __attribute__((ext_vector_type(4)));

#define NR 8192
#define ED 512
#define PSTR 264

__device__ inline u16 f2bf(float f) {
    union { float f; unsigned u; } c; c.f = f;
    unsigned u = c.u;
    u += 0x7FFFu + ((u >> 16) & 1u);
    return (u16)(u >> 16);
}
__device__ inline float bf2f(u16 h) {
    union { unsigned u; float f; } c; c.u = ((unsigned)h) << 16; return c.f;
}
__device__ inline short8 load_cvt8(const float* p) {
    const fvec4* q = (const fvec4*)p;
    fvec4 a = q[0], b = q[1];
    short8 r;
    r[0] = (short)f2bf(a[0]); r[1] = (short)f2bf(a[1]);
    r[2] = (short)f2bf(a[2]); r[3] = (short)f2bf(a[3]);
    r[4] = (short)f2bf(b[0]); r[5] = (short)f2bf(b[1]);
    r[6] = (short)f2bf(b[2]); r[7] = (short)f2bf(b[3]);
    return r;
}
__device__ inline void gload16(const void* g, void* l) {
    __builtin_amdgcn_global_load_lds(
        (const __attribute__((address_space(1))) u32*)g,
        (__attribute__((address_space(3))) u32*)l, 16, 0, 0);
}

// T2 swizzle helpers (both-sides involution, 16B-chunk preserving):
//   stage: global col chunk = (lane&7) ^ (lane>>3)   [lane>>3 == (row within octet)]
//   read:  u16 col ^= (row&7)*8
#define SWZ_SCOL(lane) ((((lane) & 7) ^ ((lane) >> 3)) * 8)
#define SWZ_RD(col, row) ((col) ^ (((row) & 7) * 8))

// K0: one-shot f32 -> bf16 conversion of x and the three W's.
__global__ __launch_bounds__(256) void cvt_kernel(
    const float* __restrict__ x, const float* __restrict__ Wq,
    const float* __restrict__ Wk, const float* __restrict__ Wv,
    u16* __restrict__ xb, u16* __restrict__ wb)
{
    int tid = blockIdx.x * 256 + threadIdx.x;
    const float* src; u16* dst; int off;
    if (tid < 524288)      { src = x;  dst = xb;          off = tid; }
    else if (tid < 557056) { src = Wq; dst = wb;          off = tid - 524288; }
    else if (tid < 589824) { src = Wk; dst = wb + 262144; off = tid - 557056; }
    else                   { src = Wv; dst = wb + 524288; off = tid - 589824; }
    *(short8*)(dst + (size_t)off * 8) = load_cvt8(src + (size_t)off * 8);
}

// K1: 128x128-tile LDS-staged GEMM (swizzled): q,k row-major; k also transposed; v transposed.
__global__ __launch_bounds__(256, 3) void qkv_kernel(
    const u16* __restrict__ xb, const u16* __restrict__ wb,
    const float* __restrict__ bq, const float* __restrict__ bk, const float* __restrict__ bv,
    u16* __restrict__ qb, u16* __restrict__ kb, u16* __restrict__ kT, u16* __restrict__ vT)
{
    __shared__ u16 ldsA[128][64];
    __shared__ u16 ldsB[128][64];

    const int lane = threadIdx.x & 63;
    const int w = threadIdx.x >> 6;
    const int ln = lane & 15;
    const int kg = lane >> 4;
    const int wr = w >> 1, wc = w & 1;
    const int z = blockIdx.z;
    const int R0 = blockIdx.y * 128;
    const int C0 = blockIdx.x * 128;
    const int srow = lane >> 3;
    const int scol = SWZ_SCOL(lane);

    const u16* B = wb + (size_t)z * 262144;
    const float* bias = (z == 0) ? bq : (z == 1) ? bk : bv;

    fvec4 acc[4][4];
    #pragma unroll
    for (int m = 0; m < 4; ++m)
        #pragma unroll
        for (int n = 0; n < 4; ++n) acc[m][n] = (fvec4){0.f, 0.f, 0.f, 0.f};

    for (int kt = 0; kt < 8; ++kt) {
        const int k0 = kt * 64;
        __syncthreads();
        #pragma unroll
        for (int i = 0; i < 4; ++i) {
            const int ra = (i * 4 + w) * 8;
            gload16(xb + (size_t)(R0 + ra + srow) * ED + k0 + scol, &ldsA[ra][0]);
            gload16(B  + (size_t)(C0 + ra + srow) * ED + k0 + scol, &ldsB[ra][0]);
        }
        __syncthreads();
        short8 af[2][4], bf8[2][4];
        #pragma unroll
        for (int kk = 0; kk < 2; ++kk) {
            #pragma unroll
            for (int m = 0; m < 4; ++m) {
                const int row = wr * 64 + m * 16 + ln;
                af[kk][m] = *(const short8*)&ldsA[row][SWZ_RD(kk * 32 + kg * 8, row)];
            }
            #pragma unroll
            for (int n = 0; n < 4; ++n) {
                const int row = wc * 64 + n * 16 + ln;
                bf8[kk][n] = *(const short8*)&ldsB[row][SWZ_RD(kk * 32 + kg * 8, row)];
            }
        }
        #pragma unroll
        for (int kk = 0; kk < 2; ++kk)
            #pragma unroll
            for (int m = 0; m < 4; ++m)
                #pragma unroll
                for (int n = 0; n < 4; ++n)
                    acc[m][n] = __builtin_amdgcn_mfma_f32_16x16x32_bf16(af[kk][m], bf8[kk][n], acc[m][n], 0, 0, 0);
    }

    #pragma unroll
    for (int n = 0; n < 4; ++n) {
        const int gcol = C0 + wc * 64 + n * 16 + ln;
        const float bc = bias[gcol];
        #pragma unroll
        for (int m = 0; m < 4; ++m) {
            #pragma unroll
            for (int r = 0; r < 4; ++r) {
                const int grow = R0 + wr * 64 + m * 16 + kg * 4 + r;
                u16 val = f2bf(acc[m][n][r] + bc);
                if (z == 0) {
                    qb[(size_t)grow * ED + gcol] = val;
                } else if (z == 1) {
                    kb[(size_t)grow * ED + gcol] = val;
                    kT[(size_t)gcol * NR + grow] = val;
                } else {
                    vT[(size_t)gcol * NR + grow] = val;
                }
            }
        }
    }
}

// K2: G = K^T K (512x512, f32 accum, stored bf16). 4 interleaved acc chains for ILP.
__global__ __launch_bounds__(256) void gram_kernel(
    const u16* __restrict__ kT, u16* __restrict__ Gb)
{
    const int lane = threadIdx.x & 63;
    const int ln = lane & 15;
    const int kg = lane >> 4;
    const int idx = blockIdx.x * 4 + (threadIdx.x >> 6);
    const int i0 = (idx >> 5) * 16, l0 = (idx & 31) * 16;

    fvec4 acc[4];
    #pragma unroll
    for (int c = 0; c < 4; ++c) acc[c] = (fvec4){0.f, 0.f, 0.f, 0.f};
    const u16* arow = kT + (size_t)(i0 + ln) * NR + kg * 8;
    const u16* brow = kT + (size_t)(l0 + ln) * NR + kg * 8;
    #pragma unroll 8
    for (int t = 0; t < 256; ++t) {
        acc[t & 3] = __builtin_amdgcn_mfma_f32_16x16x32_bf16(
            *(const short8*)(arow + t * 32), *(const short8*)(brow + t * 32), acc[t & 3], 0, 0, 0);
    }
    fvec4 s = acc[0] + acc[1] + acc[2] + acc[3];
    #pragma unroll
    for (int r = 0; r < 4; ++r)
        Gb[(size_t)(i0 + kg * 4 + r) * ED + l0 + ln] = f2bf(s[r]);
}

// K3: rn = 1/max(sqrt(q^T G q), eps), 2 acc chains.
__global__ __launch_bounds__(256) void rn_kernel(
    const u16* __restrict__ qb, const u16* __restrict__ Gb, float* __restrict__ rn)
{
    const int lane = threadIdx.x & 63;
    const int wv = threadIdx.x >> 6;
    const int ln = lane & 15;
    const int kg = lane >> 4;
    const int m0 = blockIdx.x * 64 + wv * 16;

    short8 afr[16];
    const u16* qrow = qb + (size_t)(m0 + ln) * ED + kg * 8;
    #pragma unroll
    for (int t = 0; t < 16; ++t) afr[t] = *(const short8*)(qrow + t * 32);

    float ss[4] = {0.f, 0.f, 0.f, 0.f};
    for (int e = 0; e < 32; ++e) {
        fvec4 a0 = (fvec4){0.f, 0.f, 0.f, 0.f};
        fvec4 a1 = (fvec4){0.f, 0.f, 0.f, 0.f};
        const u16* grow = Gb + (size_t)(e * 16 + ln) * ED + kg * 8;
        #pragma unroll
        for (int t = 0; t < 16; t += 2) {
            a0 = __builtin_amdgcn_mfma_f32_16x16x32_bf16(afr[t],     *(const short8*)(grow + t * 32),       a0, 0, 0, 0);
            a1 = __builtin_amdgcn_mfma_f32_16x16x32_bf16(afr[t + 1], *(const short8*)(grow + (t + 1) * 32), a1, 0, 0, 0);
        }
        fvec4 acc = a0 + a1;
        #pragma unroll
        for (int r = 0; r < 4; ++r)
            ss[r] += acc[r] * bf2f(qb[(size_t)(m0 + kg * 4 + r) * ED + e * 16 + ln]);
    }
    #pragma unroll
    for (int r = 0; r < 4; ++r) {
        float v = ss[r];
        v += __shfl_xor(v, 1); v += __shfl_xor(v, 2);
        v += __shfl_xor(v, 4); v += __shfl_xor(v, 8);
        ss[r] = v;
    }
    if (ln == 0) {
        #pragma unroll
        for (int r = 0; r < 4; ++r)
            rn[m0 + kg * 4 + r] = 1.0f / fmaxf(sqrtf(ss[r]), 1e-12f);
    }
}

// K4: P = exp((Q K^T) * rn) bf16 + dsum row sums. 128x128 tile, swizzled LDS.
__global__ __launch_bounds__(256, 3) void sexp_kernel(
    const u16* __restrict__ qb, const u16* __restrict__ kb,
    const float* __restrict__ rn, u16* __restrict__ P, float* __restrict__ dsum)
{
    __shared__ u16 ldsA[128][64];
    __shared__ u16 ldsB[128][64];

    const int lane = threadIdx.x & 63;
    const int w = threadIdx.x >> 6;
    const int ln = lane & 15;
    const int kg = lane >> 4;
    const int wr = w >> 1, wc = w & 1;
    const int R0 = blockIdx.y * 128;
    const int C0 = blockIdx.x * 128;
    const int srow = lane >> 3;
    const int scol = SWZ_SCOL(lane);

    fvec4 acc[4][4];
    #pragma unroll
    for (int m = 0; m < 4; ++m)
        #pragma unroll
        for (int n = 0; n < 4; ++n) acc[m][n] = (fvec4){0.f, 0.f, 0.f, 0.f};

    for (int kt = 0; kt < 8; ++kt) {
        const int k0 = kt * 64;
        __syncthreads();
        #pragma unroll
        for (int i = 0; i < 4; ++i) {
            const int ra = (i * 4 + w) * 8;
            gload16(qb + (size_t)(R0 + ra + srow) * ED + k0 + scol, &ldsA[ra][0]);
            gload16(kb + (size_t)(C0 + ra + srow) * ED + k0 + scol, &ldsB[ra][0]);
        }
        __syncthreads();
        short8 af[2][4], bf8[2][4];
        #pragma unroll
        for (int kk = 0; kk < 2; ++kk) {
            #pragma unroll
            for (int m = 0; m < 4; ++m) {
                const int row = wr * 64 + m * 16 + ln;
                af[kk][m] = *(const short8*)&ldsA[row][SWZ_RD(kk * 32 + kg * 8, row)];
            }
            #pragma unroll
            for (int n = 0; n < 4; ++n) {
                const int row = wc * 64 + n * 16 + ln;
                bf8[kk][n] = *(const short8*)&ldsB[row][SWZ_RD(kk * 32 + kg * 8, row)];
            }
        }
        #pragma unroll
        for (int kk = 0; kk < 2; ++kk)
            #pragma unroll
            for (int m = 0; m < 4; ++m)
                #pragma unroll
                for (int n = 0; n < 4; ++n)
                    acc[m][n] = __builtin_amdgcn_mfma_f32_16x16x32_bf16(af[kk][m], bf8[kk][n], acc[m][n], 0, 0, 0);
    }

    #pragma unroll
    for (int m = 0; m < 4; ++m) {
        float dpart[4] = {0.f, 0.f, 0.f, 0.f};
        #pragma unroll
        for (int r = 0; r < 4; ++r) {
            const int grow = R0 + wr * 64 + m * 16 + kg * 4 + r;
            const float rv = rn[grow];
            #pragma unroll
            for (int n = 0; n < 4; ++n) {
                const int gcol = C0 + wc * 64 + n * 16 + ln;
                u16 pb = f2bf(__expf(acc[m][n][r] * rv));
                P[(size_t)grow * NR + gcol] = pb;
                dpart[r] += bf2f(pb);
            }
        }
        #pragma unroll
        for (int r = 0; r < 4; ++r) {
            float v = dpart[r];
            v += __shfl_xor(v, 1); v += __shfl_xor(v, 2);
            v += __shfl_xor(v, 4); v += __shfl_xor(v, 8);
            if (ln == 0)
                atomicAdd(&dsum[R0 + wr * 64 + m * 16 + kg * 4 + r], v);
        }
    }
}

// K5: partial PV, 128x256 output tile, 512 threads, split-K=2, swizzled LDS.
// P read only 2x (once per ks) instead of 4x.
__global__ __launch_bounds__(512, 2) void pv_kernel(
    const u16* __restrict__ P, const u16* __restrict__ vT, float* __restrict__ part)
{
    __shared__ u16 ldsA[128][64];   // P slab: 128 rows x 64 k
    __shared__ u16 ldsB[256][64];   // vT slab: 256 out-cols x 64 k

    const int lane = threadIdx.x & 63;
    const int w = threadIdx.x >> 6;       // 0..7
    const int ln = lane & 15;
    const int kg = lane >> 4;
    const int wr = w >> 2, wc = w & 3;    // 2 x 4 wave grid
    const int R0 = blockIdx.y * 128;
    const int C0 = blockIdx.x * 256;
    const int ks = blockIdx.z;
    const int srow = lane >> 3;
    const int scol = SWZ_SCOL(lane);

    float* pp = part + (size_t)ks * NR * ED;

    fvec4 acc[4][4];
    #pragma unroll
    for (int m = 0; m < 4; ++m)
        #pragma unroll
        for (int n = 0; n < 4; ++n) acc[m][n] = (fvec4){0.f, 0.f, 0.f, 0.f};

    for (int kt = 0; kt < 64; ++kt) {
        const int k0 = ks * 4096 + kt * 64;
        __syncthreads();
        #pragma unroll
        for (int i = 0; i < 2; ++i) {
            const int ra = (i * 8 + w) * 8;
            gload16(P + (size_t)(R0 + ra + srow) * NR + k0 + scol, &ldsA[ra][0]);
        }
        #pragma unroll
        for (int i = 0; i < 4; ++i) {
            const int rb = (i * 8 + w) * 8;
            gload16(vT + (size_t)(C0 + rb + srow) * NR + k0 + scol, &ldsB[rb][0]);
        }
        __syncthreads();
        short8 af[2][4], bf8[2][4];
        #pragma unroll
        for (int kk = 0; kk < 2; ++kk) {
            #pragma unroll
            for (int m = 0; m < 4; ++m) {
                const int row = wr * 64 + m * 16 + ln;
                af[kk][m] = *(const short8*)&ldsA[row][SWZ_RD(kk * 32 + kg * 8, row)];
            }
            #pragma unroll
            for (int n = 0; n < 4; ++n) {
                const int row = wc * 64 + n * 16 + ln;
                bf8[kk][n] = *(const short8*)&ldsB[row][SWZ_RD(kk * 32 + kg * 8, row)];
            }
        }
        #pragma unroll
        for (int kk = 0; kk < 2; ++kk)
            #pragma unroll
            for (int m = 0; m < 4; ++m)
                #pragma unroll
                for (int n = 0; n < 4; ++n)
                    acc[m][n] = __builtin_amdgcn_mfma_f32_16x16x32_bf16(af[kk][m], bf8[kk][n], acc[m][n], 0, 0, 0);
    }

    #pragma unroll
    for (int m = 0; m < 4; ++m) {
        #pragma unroll
        for (int r = 0; r < 4; ++r) {
            const int grow = R0 + wr * 64 + m * 16 + kg * 4 + r;
            #pragma unroll
            for (int n = 0; n < 4; ++n) {
                const int gcol = C0 + wc * 64 + n * 16 + ln;
                pp[(size_t)grow * ED + gcol] = acc[m][n][r];
            }
        }
    }
}

// K6: out = (part0 + part1) / dsum
__global__ __launch_bounds__(256) void reduce_kernel(
    const float* __restrict__ part, const float* __restrict__ dsum, float* __restrict__ out)
{
    const size_t idx = ((size_t)blockIdx.x * 256 + threadIdx.x) * 4;
    const int row = (int)(idx >> 9);
    const float iv = 1.0f / dsum[row];
    fvec4 a = *(const fvec4*)(part + idx);
    fvec4 b = *(const fvec4*)(part + (size_t)NR * ED + idx);
    fvec4 o;
    #pragma unroll
    for (int i = 0; i < 4; ++i) o[i] = (a[i] + b[i]) * iv;
    *(fvec4*)(out + idx) = o;
}

// Fallback fused attention (R2 path) if ws is too small for P.
__global__ __launch_bounds__(512, 2) void attn_kernel(
    const u16* __restrict__ qb, const u16* __restrict__ kb,
    const u16* __restrict__ vT, const float* __restrict__ rn, float* __restrict__ out)
{
    __shared__ u16 p_lds[2 * 16 * PSTR];
    __shared__ float red[2][4][16];

    const int lane = threadIdx.x & 63;
    const int w = threadIdx.x >> 6;
    const int ln = lane & 15;
    const int kg = lane >> 4;
    const int rh = w >> 2;
    const int jg = w & 3;
    const int R0 = blockIdx.x * 32 + rh * 16;

    short8 afr[16];
    const u16* qrow = qb + (size_t)(R0 + ln) * ED + kg * 8;
    #pragma unroll
    for (int t = 0; t < 16; ++t) afr[t] = *(const short8*)(qrow + t * 32);

    float rnv[4];
    #pragma unroll
    for (int r = 0; r < 4; ++r) rnv[r] = rn[R0 + kg * 4 + r];

    fvec4 oacc[8];
    #pragma unroll
    for (int e = 0; e < 8; ++e) oacc[e] = (fvec4){0.f, 0.f, 0.f, 0.f};
    float dsum[4] = {0.f, 0.f, 0.f, 0.f};

    u16* pw = p_lds + rh * 16 * PSTR;

    for (int c = 0; c < 32; ++c) {
        const int j0 = c * 256 + jg * 64;
        fvec4 acc[4];
        #pragma unroll
        for (int jt = 0; jt < 4; ++jt) acc[jt] = (fvec4){0.f, 0.f, 0.f, 0.f};
        const u16* kbase = kb + (size_t)(j0 + ln) * ED + kg * 8;
        #pragma unroll 4
        for (int t = 0; t < 16; ++t) {
            short8 af = afr[t];
            #pragma unroll
            for (int jt = 0; jt < 4; ++jt) {
                short8 bfr = *(const short8*)(kbase + (size_t)jt * 16 * ED + t * 32);
                acc[jt] = __builtin_amdgcn_mfma_f32_16x16x32_bf16(af, bfr, acc[jt], 0, 0, 0);
            }
        }
        #pragma unroll
        for (int jt = 0; jt < 4; ++jt) {
            #pragma unroll
            for (int r = 0; r < 4; ++r) {
                float p = __expf(acc[jt][r] * rnv[r]);
                dsum[r] += p;
                pw[(kg * 4 + r) * PSTR + jg * 64 + jt * 16 + ln] = f2bf(p);
            }
        }
        __syncthreads();
        const u16* vbase = vT + (size_t)(jg * 128 + ln) * NR + c * 256 + kg * 8;
        const u16* prow = pw + ln * PSTR + kg * 8;
        #pragma unroll
        for (int kk = 0; kk < 8; ++kk) {
            short8 afp = *(const short8*)(prow + kk * 32);
            #pragma unroll
            for (int e = 0; e < 8; ++e) {
                short8 bfr = *(const short8*)(vbase + (size_t)e * 16 * NR + kk * 32);
                oacc[e] = __builtin_amdgcn_mfma_f32_16x16x32_bf16(afp, bfr, oacc[e], 0, 0, 0);
            }
        }
        __syncthreads();
    }

    #pragma unroll
    for (int r = 0; r < 4; ++r) {
        float v = dsum[r];
        v += __shfl_xor(v, 1); v += __shfl_xor(v, 2);
        v += __shfl_xor(v, 4); v += __shfl_xor(v, 8);
        dsum[r] = v;
    }
    if (ln == 0) {
        #pragma unroll
        for (int r = 0; r < 4; ++r) red[rh][jg][kg * 4 + r] = dsum[r];
    }
    __syncthreads();
    float inv[4];
    #pragma unroll
    for (int r = 0; r < 4; ++r) {
        const int row = kg * 4 + r;
        inv[r] = 1.0f / (red[rh][0][row] + red[rh][1][row] + red[rh][2][row] + red[rh][3][row]);
    }
    #pragma unroll
    for (int e = 0; e < 8; ++e) {
        #pragma unroll
        for (int r = 0; r < 4; ++r)
            out[(size_t)(R0 + kg * 4 + r) * ED + jg * 128 + e * 16 + ln] = oacc[e][r] * inv[r];
    }
}

extern "C" void kernel_launch(void* const* d_in, const int* in_sizes, int n_in,
                              void* d_out, int out_size, void* d_ws, size_t ws_size,
                              hipStream_t stream) {
    const float* x  = (const float*)d_in[0];
    const float* Wq = (const float*)d_in[1];
    const float* bq = (const float*)d_in[2];
    const float* Wk = (const float*)d_in[3];
    const float* bk = (const float*)d_in[4];
    const float* Wv = (const float*)d_in[5];
    const float* bv = (const float*)d_in[6];
    float* out = (float*)d_out;

    u16* xb = (u16*)d_ws;                          // 8 MB
    u16* wb = xb + (size_t)NR * ED;                // 1.5 MB
    u16* qb = wb + 3 * 262144;                     // 8 MB
    u16* kb = qb + (size_t)NR * ED;                // 8 MB
    u16* kT = kb + (size_t)NR * ED;                // 8 MB
    u16* vT = kT + (size_t)NR * ED;                // 8 MB  (byte offset 33.5 MB)
    u16* Gb = vT + (size_t)NR * ED;                // 0.5 MB
    float* rn   = (float*)(Gb + 262144);           // 32 KB
    float* dsum = rn + NR;                         // 32 KB
    u16* P = (u16*)(dsum + NR);                    // 128 MB
    // pv partials (2 x 16 MB f32) alias the dead xb/wb/qb/kb/kT region (first 32 MB).
    float* part = (float*)d_ws;

    const size_t need = (size_t)((u16*)(dsum + NR) - (u16*)d_ws) * 2 + (size_t)NR * NR * 2;

    cvt_kernel<<<2432, 256, 0, stream>>>(x, Wq, Wk, Wv, xb, wb);
    dim3 g1(ED / 128, NR / 128, 3);
    qkv_kernel<<<g1, 256, 0, stream>>>(xb, wb, bq, bk, bv, qb, kb, kT, vT);
    gram_kernel<<<256, 256, 0, stream>>>(kT, Gb);
    rn_kernel<<<128, 256, 0, stream>>>(qb, Gb, rn);

    if (ws_size >= need) {
        hipMemsetAsync(dsum, 0, NR * sizeof(float), stream);
        dim3 gs(NR / 128, NR / 128);
        sexp_kernel<<<gs, 256, 0, stream>>>(qb, kb, rn, P, dsum);
        dim3 gp(ED / 256, NR / 128, 2);
        pv_kernel<<<gp, 512, 0, stream>>>(P, vT, part);
        reduce_kernel<<<NR * ED / 4 / 256, 256, 0, stream>>>(part, dsum, out);
    } else {
        attn_kernel<<<NR / 32, 512, 0, stream>>>(qb, kb, vT, rn, out);
    }
}